// Round 2
// baseline (17882.726 us; speedup 1.0000x reference)
//
#include <hip/hip_runtime.h>

// ---------------------------------------------------------------------------
// BiDAF block: B=32, CLEN=384, QLEN=64, H=768
// Workspace budget ~227MB (round-0 fault suspected ws overflow at 340MB):
//   [0, 75.5MB)    g  (later: mA @0, mB @37.7MB, m2 @0)
//   [75.5, 226.5)  xg (attention temps alias the front of this region)
//   [226.5, +368K) tail scalars (proj, smax, bw, q2c, pg1/pg2, barriers)
// ---------------------------------------------------------------------------

typedef __bf16 bf16_t;
typedef __bf16 bf16x8 __attribute__((ext_vector_type(8)));
typedef float  f32x4  __attribute__((ext_vector_type(4)));

#define TT 384

__device__ __forceinline__ void gload_lds16(const void* g, void* l) {
  __builtin_amdgcn_global_load_lds((const __attribute__((address_space(1))) void*)g,
                                   (__attribute__((address_space(3))) void*)l, 16, 0, 0);
}

__global__ void k_zero(unsigned* p) { p[threadIdx.x] = 0u; }

// ---------------------------------------------------------------------------
// GEMM: C[M,N] = A[M,K] * B[N,K]^T, A bf16 K-contig (global_load_lds).
// BSRC=0: B bf16 via global_load_lds (Bv + bz*sBb). BSRC=1: B fp32 from
// Bv (rows < nsplit) / Bv2 (rows >= nsplit), converted during staging.
// BM=128, BK=32, 256 threads = 4 waves (2x2), wave tile 64 x (BN/2).
// EPI=0: bf16 out. EPI=1: f32 out + rowb[bz*M+row] + colb[bz*N+col] + *sb.
// ---------------------------------------------------------------------------
template<int BN, int EPI, int BSRC>
__global__ __launch_bounds__(256) void k_gemm(
    const bf16_t* __restrict__ A, const void* __restrict__ Bv, const void* __restrict__ Bv2,
    int nsplit, void* __restrict__ Cv,
    int M, int N, int K, long sAb, long sBb, long sCb,
    const float* __restrict__ rowb, const float* __restrict__ colb,
    const float* __restrict__ sb)
{
  constexpr int BM = 128, BK = 32;
  constexpr int NT = BN / 32;          // 16-wide N tiles per wave
  __shared__ bf16_t sA[BM * BK];
  __shared__ bf16_t sB[BN * BK];
  const int t    = threadIdx.x;
  const int lane = t & 63;
  const int wm   = (t >> 6) >> 1, wn = (t >> 6) & 1;
  const long bz  = blockIdx.z;
  const int nbase = blockIdx.y * BN;
  const bf16_t* Ab = A + bz * sAb + (long)blockIdx.x * BM * K;
  const bf16_t* Bb = nullptr;
  const float*  Bf = nullptr;
  if constexpr (BSRC == 0)
    Bb = (const bf16_t*)Bv + bz * sBb + (long)nbase * K;
  else
    Bf = (nbase < nsplit) ? ((const float*)Bv  + (long)nbase * K)
                          : ((const float*)Bv2 + (long)(nbase - nsplit) * K);

  const int r4 = t >> 2;                          // staging row 0..63
  const int kq = (t & 3) ^ ((r4 >> 1) & 3);       // XOR-swizzled source k-quad

  f32x4 acc[4][NT];
  #pragma unroll
  for (int i = 0; i < 4; i++)
    #pragma unroll
    for (int j = 0; j < NT; j++) acc[i][j] = (f32x4){0.f, 0.f, 0.f, 0.f};

  const int mrow = lane & 15;
  const int fq   = lane >> 4;
  const int aswz = (fq ^ ((mrow >> 1) & 3)) * 8;  // swizzled frag k-offset (elems)

  for (int k0 = 0; k0 < K; k0 += BK) {
    __syncthreads();
    gload_lds16(Ab + (long)r4 * K + k0 + kq * 8,        (char*)sA + t * 16);
    gload_lds16(Ab + (long)(64 + r4) * K + k0 + kq * 8, (char*)sA + 4096 + t * 16);
    if constexpr (BSRC == 0) {
      gload_lds16(Bb + (long)r4 * K + k0 + kq * 8,        (char*)sB + t * 16);
      if constexpr (BN == 128)
        gload_lds16(Bb + (long)(64 + r4) * K + k0 + kq * 8, (char*)sB + 4096 + t * 16);
    } else {
      {
        f32x4 b0 = *(const f32x4*)(Bf + (long)r4 * K + k0 + kq * 8);
        f32x4 b1 = *(const f32x4*)(Bf + (long)r4 * K + k0 + kq * 8 + 4);
        bf16x8 bb;
        #pragma unroll
        for (int e = 0; e < 4; e++) { bb[e] = (bf16_t)b0[e]; bb[e + 4] = (bf16_t)b1[e]; }
        *(bf16x8*)((char*)sB + t * 16) = bb;
      }
      if constexpr (BN == 128) {
        f32x4 b0 = *(const f32x4*)(Bf + (long)(64 + r4) * K + k0 + kq * 8);
        f32x4 b1 = *(const f32x4*)(Bf + (long)(64 + r4) * K + k0 + kq * 8 + 4);
        bf16x8 bb;
        #pragma unroll
        for (int e = 0; e < 4; e++) { bb[e] = (bf16_t)b0[e]; bb[e + 4] = (bf16_t)b1[e]; }
        *(bf16x8*)((char*)sB + 4096 + t * 16) = bb;
      }
    }
    __syncthreads();

    bf16x8 af[4], bv[NT];
    #pragma unroll
    for (int mt = 0; mt < 4; mt++)
      af[mt] = *(const bf16x8*)(sA + (wm * 64 + mt * 16 + mrow) * 32 + aswz);
    #pragma unroll
    for (int nt = 0; nt < NT; nt++)
      bv[nt] = *(const bf16x8*)(sB + (wn * (BN / 2) + nt * 16 + mrow) * 32 + aswz);
    #pragma unroll
    for (int mt = 0; mt < 4; mt++)
      #pragma unroll
      for (int nt = 0; nt < NT; nt++)
        acc[mt][nt] = __builtin_amdgcn_mfma_f32_16x16x32_bf16(af[mt], bv[nt], acc[mt][nt], 0, 0, 0);
  }

  const int rbase = (lane >> 4) * 4;
  #pragma unroll
  for (int mt = 0; mt < 4; mt++)
    #pragma unroll
    for (int nt = 0; nt < NT; nt++)
      #pragma unroll
      for (int r = 0; r < 4; r++) {
        int grow = blockIdx.x * BM + wm * 64 + mt * 16 + rbase + r;
        int gcol = nbase + wn * (BN / 2) + nt * 16 + (lane & 15);
        if constexpr (EPI == 0) {
          ((bf16_t*)Cv)[bz * sCb + (long)grow * N + gcol] = (bf16_t)acc[mt][nt][r];
        } else {
          ((float*)Cv)[bz * sCb + (long)grow * N + gcol] =
              acc[mt][nt][r] + rowb[bz * M + grow] + colb[bz * N + gcol] + sb[0];
        }
      }
}

// ---------------------------------------------------------------------------
// Recurrent biLSTM stage. grid = 96 (48 slices x 2 dirs), 256 threads.
// Each WG: j-slice of 16 h-cols; whh rows {g*768+j0+jj} resident in LDS (bf16).
// One device-scope barrier per timestep per direction (48 blocks each).
// xg: [B*T, 6144] bf16 (fwd 4H | bwd 4H, gate order i,f,g,o).
// mout: [B, T, 2H] bf16 (fwd | bwd).
// ---------------------------------------------------------------------------
__global__ __launch_bounds__(256) void k_lstm(
    const bf16_t* __restrict__ xg, bf16_t* __restrict__ mout,
    const float* __restrict__ whh_f, const float* __restrict__ whh_b,
    const float* __restrict__ bias_f, const float* __restrict__ bias_b,
    unsigned* __restrict__ bar)
{
  __shared__ bf16_t sW[64 * 776];   // 99,328 B
  __shared__ bf16_t sH[32 * 776];   // 49,664 B
  __shared__ float  sG[4 * 512];    //  8,192 B  => 157,184 B total (<160K)
  const int t    = threadIdx.x;
  const int lane = t & 63;
  const int wg   = t >> 6;                 // wave index == gate index
  const int blk  = blockIdx.x;
  const int dir  = blk / 48;
  const int j0   = (blk - dir * 48) * 16;
  const float* whh  = dir ? whh_b : whh_f;
  const float* bias = dir ? bias_b : bias_f;
  unsigned* mybar = bar + dir * 16;

  // stage whh slice -> LDS bf16 (rows r = g*16+jj -> whh[g*768+j0+jj, :])
  for (int r = 0; r < 64; r++) {
    const float* src = whh + (long)((r >> 4) * 768 + j0 + (r & 15)) * 768;
    for (int c0 = t; c0 < 768; c0 += 256) sW[r * 776 + c0] = (bf16_t)src[c0];
  }
  float bsv[4];
  #pragma unroll
  for (int gi = 0; gi < 4; gi++) bsv[gi] = bias[gi * 768 + j0 + (t & 15)];

  float cst0 = 0.f, cst1 = 0.f;
  unsigned gen = 0;
  const int mrow = lane & 15;
  const int fq   = lane >> 4;
  const int boff  = (wg * 16 + mrow) * 776 + fq * 8;
  const int aoff0 = mrow * 776 + fq * 8;
  const int aoff1 = (16 + mrow) * 776 + fq * 8;

  for (int s = 0; s < TT; s++) {
    const int tc = dir ? (TT - 1 - s) : s;
    if (s == 0) {
      #pragma unroll
      for (int rep = 0; rep < 12; rep++) {
        int e = rep * 2048 + t * 8;
        int row = e / 768, col = e - row * 768;
        *(f32x4*)(sH + row * 776 + col) = (f32x4){0.f, 0.f, 0.f, 0.f};
      }
    } else {
      const int tp = dir ? tc + 1 : tc - 1;
      #pragma unroll
      for (int rep = 0; rep < 12; rep++) {
        int e = rep * 2048 + t * 8;
        int row = e / 768, col = e - row * 768;
        bf16x8 v = *(const bf16x8*)(mout + (long)(row * TT + tp) * 1536 + dir * 768 + col);
        *(bf16x8*)(sH + row * 776 + col) = v;
      }
    }
    __syncthreads();

    f32x4 a0 = (f32x4){0.f,0.f,0.f,0.f}, a1 = (f32x4){0.f,0.f,0.f,0.f};
    #pragma unroll
    for (int kc = 0; kc < 24; kc++) {
      bf16x8 bv  = *(const bf16x8*)(sW + boff + kc * 32);
      bf16x8 av0 = *(const bf16x8*)(sH + aoff0 + kc * 32);
      bf16x8 av1 = *(const bf16x8*)(sH + aoff1 + kc * 32);
      a0 = __builtin_amdgcn_mfma_f32_16x16x32_bf16(av0, bv, a0, 0, 0, 0);
      a1 = __builtin_amdgcn_mfma_f32_16x16x32_bf16(av1, bv, a1, 0, 0, 0);
    }
    #pragma unroll
    for (int r = 0; r < 4; r++) {
      sG[wg * 512 + (fq * 4 + r) * 16 + mrow]        = a0[r];
      sG[wg * 512 + (16 + fq * 4 + r) * 16 + mrow]   = a1[r];
    }
    __syncthreads();

    #pragma unroll
    for (int ui = 0; ui < 2; ui++) {
      int u = t + ui * 256;
      int b = u >> 4, jj = u & 15;
      long xr = (long)(b * TT + tc) * 6144 + dir * 3072 + j0 + jj;
      float gi = sG[0 * 512 + u] + (float)xg[xr]        + bsv[0];
      float gf = sG[1 * 512 + u] + (float)xg[xr + 768]  + bsv[1];
      float gg = sG[2 * 512 + u] + (float)xg[xr + 1536] + bsv[2];
      float go = sG[3 * 512 + u] + (float)xg[xr + 2304] + bsv[3];
      gi = 1.f / (1.f + __expf(-gi));
      gf = 1.f / (1.f + __expf(-gf));
      gg = 1.f - 2.f / (__expf(2.f * gg) + 1.f);
      go = 1.f / (1.f + __expf(-go));
      float& cs = ui ? cst1 : cst0;
      cs = gf * cs + gi * gg;
      float hv = go * (1.f - 2.f / (__expf(2.f * cs) + 1.f));
      mout[(long)(b * TT + tc) * 1536 + dir * 768 + j0 + jj] = (bf16_t)hv;
    }

    // per-direction grid barrier (48 blocks), monotonic counter
    gen += 48;
    __syncthreads();
    if (t == 0) {
      __threadfence();
      __hip_atomic_fetch_add(mybar, 1u, __ATOMIC_RELAXED, __HIP_MEMORY_SCOPE_AGENT);
      while (__hip_atomic_load(mybar, __ATOMIC_RELAXED, __HIP_MEMORY_SCOPE_AGENT) < gen)
        __builtin_amdgcn_s_sleep(1);
    }
    __syncthreads();
    __threadfence();
  }
}

// --------------------------- attention helpers -----------------------------

__global__ __launch_bounds__(256) void k_pack(
    const float* __restrict__ c, const float* __restrict__ q,
    const float* __restrict__ wcq, bf16_t* __restrict__ cw, bf16_t* __restrict__ qb)
{
  int i = blockIdx.x * 256 + threadIdx.x;        // 43008 blocks -> 11,010,048
  if (i < 9437184) {
    int h = i % 768;
    cw[i] = (bf16_t)(c[i] * wcq[h]);
  } else {
    int j = i - 9437184;
    qb[j] = (bf16_t)q[j];
  }
}

__global__ __launch_bounds__(256) void k_proj(
    const float* __restrict__ c, const float* __restrict__ q,
    const float* __restrict__ wc, const float* __restrict__ bc,
    const float* __restrict__ wq, const float* __restrict__ bq,
    float* __restrict__ projc, float* __restrict__ projq)
{
  int row  = blockIdx.x * 4 + (threadIdx.x >> 6);  // 0..14335
  int lane = threadIdx.x & 63;
  const float *src, *w;
  bool isC = row < 12288;
  if (isC) { src = c + (long)row * 768;          w = wc; }
  else     { src = q + (long)(row - 12288) * 768; w = wq; }
  float a = 0.f;
  for (int k = lane * 4; k < 768; k += 256) {
    f32x4 v = *(const f32x4*)(src + k);
    f32x4 wv = *(const f32x4*)(w + k);
    a += v[0]*wv[0] + v[1]*wv[1] + v[2]*wv[2] + v[3]*wv[3];
  }
  for (int m = 32; m; m >>= 1) a += __shfl_xor(a, m);
  if (lane == 0) {
    if (isC) projc[row] = a + bc[0];
    else     projq[row - 12288] = a + bq[0];
  }
}

__global__ __launch_bounds__(256) void k_smax_j(
    const float* __restrict__ s, bf16_t* __restrict__ a, float* __restrict__ smax)
{
  int row  = blockIdx.x * 4 + (threadIdx.x >> 6);
  int lane = threadIdx.x & 63;
  float v = s[(long)row * 64 + lane];
  float mx = v;
  for (int m = 32; m; m >>= 1) mx = fmaxf(mx, __shfl_xor(mx, m));
  float p = __expf(v - mx);
  float sum = p;
  for (int m = 32; m; m >>= 1) sum += __shfl_xor(sum, m);
  a[(long)row * 64 + lane] = (bf16_t)(p / sum);
  if (lane == 0) smax[row] = mx;
}

__global__ __launch_bounds__(384) void k_smax_i(
    const float* __restrict__ smax, float* __restrict__ bw)
{
  __shared__ float red[8];
  int b = blockIdx.x, t = threadIdx.x;   // 384 threads, 6 waves
  int lane = t & 63, wv = t >> 6;
  float v = smax[b * 384 + t];
  float mx = v;
  for (int m = 32; m; m >>= 1) mx = fmaxf(mx, __shfl_xor(mx, m));
  if (lane == 0) red[wv] = mx;
  __syncthreads();
  float gm = red[0];
  #pragma unroll
  for (int i = 1; i < 6; i++) gm = fmaxf(gm, red[i]);
  float p = __expf(v - gm);
  float sm = p;
  for (int m = 32; m; m >>= 1) sm += __shfl_xor(sm, m);
  __syncthreads();
  if (lane == 0) red[wv] = sm;
  __syncthreads();
  float tot = red[0];
  #pragma unroll
  for (int i = 1; i < 6; i++) tot += red[i];
  bw[b * 384 + t] = p / tot;
}

__global__ __launch_bounds__(256) void k_q2c(
    const float* __restrict__ bw, const float* __restrict__ c, float* __restrict__ q2c)
{
  int b = blockIdx.y;
  int h = blockIdx.x * 256 + threadIdx.x;
  const float* cb = c + (long)b * 384 * 768;
  float acc = 0.f;
  for (int i = 0; i < 384; i++) acc += bw[b * 384 + i] * cb[(long)i * 768 + h];
  q2c[b * 768 + h] = acc;
}

__global__ __launch_bounds__(256) void k_tq(
    const bf16_t* __restrict__ qb, bf16_t* __restrict__ qT)
{
  __shared__ bf16_t sT[64][72];
  int b = blockIdx.y, hc = blockIdx.x, t = threadIdx.x;
  {
    int j = t >> 2, h0 = (t & 3) * 16;
    const bf16_t* src = qb + (long)(b * 64 + j) * 768 + hc * 64 + h0;
    *(bf16x8*)&sT[j][h0]     = *(const bf16x8*)(src);
    *(bf16x8*)&sT[j][h0 + 8] = *(const bf16x8*)(src + 8);
  }
  __syncthreads();
  {
    int h = t >> 2, j0 = (t & 3) * 16;
    bf16x8 o0, o1;
    #pragma unroll
    for (int e = 0; e < 8; e++) { o0[e] = sT[j0 + e][h]; o1[e] = sT[j0 + 8 + e][h]; }
    bf16_t* dst = qT + (long)(b * 768 + hc * 64 + h) * 64 + j0;
    *(bf16x8*)dst       = o0;
    *(bf16x8*)(dst + 8) = o1;
  }
}

__global__ __launch_bounds__(256) void k_buildg(
    const float* __restrict__ c, const bf16_t* __restrict__ c2q,
    const float* __restrict__ q2c, bf16_t* __restrict__ g)
{
  int i = blockIdx.x * 256 + threadIdx.x;   // < 9,437,184
  int h = i % 768;
  int row = i / 768;
  int b = row / 384;
  float cv  = c[i];
  float cqv = (float)c2q[i];
  float qcv = q2c[b * 768 + h];
  bf16_t* gr = g + (long)row * 3072;
  gr[h]        = (bf16_t)cv;
  gr[768 + h]  = c2q[i];
  gr[1536 + h] = (bf16_t)(cv * cqv);
  gr[2304 + h] = (bf16_t)(cv * qcv);
}

// heads: g-part (both p1 and p2), one pass over g
__global__ __launch_bounds__(256) void k_headsg(
    const bf16_t* __restrict__ g, const float* __restrict__ w1, const float* __restrict__ w2,
    float* __restrict__ pg1, float* __restrict__ pg2)
{
  int row  = blockIdx.x * 4 + (threadIdx.x >> 6);  // 0..12287
  int lane = threadIdx.x & 63;
  float a1 = 0.f, a2 = 0.f;
  const bf16_t* gr = g + (long)row * 3072;
  for (int k = lane * 8; k < 3072; k += 512) {
    bf16x8 v = *(const bf16x8*)(gr + k);
    f32x4 wa = *(const f32x4*)(w1 + k), wb = *(const f32x4*)(w1 + k + 4);
    f32x4 xa = *(const f32x4*)(w2 + k), xb = *(const f32x4*)(w2 + k + 4);
    #pragma unroll
    for (int e = 0; e < 4; e++) {
      a1 += (float)v[e] * wa[e] + (float)v[e + 4] * wb[e];
      a2 += (float)v[e] * xa[e] + (float)v[e + 4] * xb[e];
    }
  }
  for (int m_ = 32; m_; m_ >>= 1) { a1 += __shfl_xor(a1, m_); a2 += __shfl_xor(a2, m_); }
  if (lane == 0) { pg1[row] = a1; pg2[row] = a2; }
}

// heads: m-part, writes final output rows
__global__ __launch_bounds__(256) void k_headsm(
    const bf16_t* __restrict__ m, const float* __restrict__ wm,
    const float* __restrict__ pg, const float* __restrict__ bg,
    const float* __restrict__ bm, float* __restrict__ out)
{
  int row  = blockIdx.x * 4 + (threadIdx.x >> 6);  // 0..12287
  int lane = threadIdx.x & 63;
  float a = 0.f;
  const bf16_t* mr = m + (long)row * 1536;
  for (int k = lane * 8; k < 1536; k += 512) {
    bf16x8 v = *(const bf16x8*)(mr + k);
    f32x4 wa = *(const f32x4*)(wm + k), wb = *(const f32x4*)(wm + k + 4);
    #pragma unroll
    for (int e = 0; e < 4; e++) a += (float)v[e] * wa[e] + (float)v[e + 4] * wb[e];
  }
  for (int m_ = 32; m_; m_ >>= 1) a += __shfl_xor(a, m_);
  if (lane == 0) out[row] = pg[row] + a + bg[0] + bm[0];
}

// ---------------------------------------------------------------------------

extern "C" void kernel_launch(void* const* d_in, const int* in_sizes, int n_in,
                              void* d_out, int out_size, void* d_ws, size_t ws_size,
                              hipStream_t stream)
{
  (void)in_sizes; (void)n_in; (void)out_size; (void)ws_size;
  const float* c    = (const float*)d_in[0];
  const float* q    = (const float*)d_in[1];
  const float* wac  = (const float*)d_in[2];
  const float* bac  = (const float*)d_in[3];
  const float* waq  = (const float*)d_in[4];
  const float* baq  = (const float*)d_in[5];
  const float* wacq = (const float*)d_in[6];
  const float* bacq = (const float*)d_in[7];
  const float* l1f_wih = (const float*)d_in[8];
  const float* l1f_whh = (const float*)d_in[9];
  const float* l1f_b   = (const float*)d_in[10];
  const float* l1b_wih = (const float*)d_in[11];
  const float* l1b_whh = (const float*)d_in[12];
  const float* l1b_b   = (const float*)d_in[13];
  const float* l2f_wih = (const float*)d_in[14];
  const float* l2f_whh = (const float*)d_in[15];
  const float* l2f_b   = (const float*)d_in[16];
  const float* l2b_wih = (const float*)d_in[17];
  const float* l2b_whh = (const float*)d_in[18];
  const float* l2b_b   = (const float*)d_in[19];
  const float* lof_wih = (const float*)d_in[20];
  const float* lof_whh = (const float*)d_in[21];
  const float* lof_b   = (const float*)d_in[22];
  const float* lob_wih = (const float*)d_in[23];
  const float* lob_whh = (const float*)d_in[24];
  const float* lob_b   = (const float*)d_in[25];
  const float* p1wg = (const float*)d_in[26];
  const float* p1bg = (const float*)d_in[27];
  const float* p1wm = (const float*)d_in[28];
  const float* p1bm = (const float*)d_in[29];
  const float* p2wg = (const float*)d_in[30];
  const float* p2bg = (const float*)d_in[31];
  const float* p2wm = (const float*)d_in[32];
  const float* p2bm = (const float*)d_in[33];

  // workspace layout (total ~226.9 MB)
  char* ws = (char*)d_ws;
  bf16_t* g_bf = (bf16_t*)ws;                       // [0, 75.5MB) g
  bf16_t* mA   = (bf16_t*)ws;                       // aliases g (g dead by stage1 lstm)
  bf16_t* mB   = (bf16_t*)(ws + 37748736L);         // second half of g region
  bf16_t* m2   = (bf16_t*)ws;                       // aliases mA (dead after stage2 GEMM)
  char*   xgc  = ws + 75497472L;                    // [75.5MB, 226.5MB) xg
  bf16_t* xg   = (bf16_t*)xgc;
  // attention temps alias the xg region (dead before stage1 GEMM writes xg)
  bf16_t* cw  = (bf16_t*)xgc;                       // 18,874,368
  bf16_t* qb  = (bf16_t*)(xgc + 18874368L);         //  3,145,728
  bf16_t* qT  = (bf16_t*)(xgc + 22020096L);         //  3,145,728
  float*  sS  = (float*) (xgc + 25165824L);         //  3,145,728
  bf16_t* aP  = (bf16_t*)(xgc + 28311552L);         //  1,572,864
  bf16_t* c2q = (bf16_t*)(xgc + 29884416L);         // 18,874,368
  char* tail = ws + 226492416L;
  float*    projc = (float*)tail;                   // 49,152
  float*    projq = (float*)(tail + 49152);         //  8,192
  float*    smax  = (float*)(tail + 57344);         // 49,152
  float*    bw    = (float*)(tail + 106496);        // 49,152
  float*    q2c   = (float*)(tail + 155648);        // 98,304
  float*    pg1   = (float*)(tail + 253952);        // 49,152
  float*    pg2   = (float*)(tail + 303104);        // 49,152
  unsigned* bar   = (unsigned*)(tail + 352256);     // 512

  k_zero<<<1, 128, 0, stream>>>(bar);

  // ---- attention ----
  k_pack<<<43008, 256, 0, stream>>>(c, q, wacq, cw, qb);
  k_proj<<<3584, 256, 0, stream>>>(c, q, wac, bac, waq, baq, projc, projq);
  k_gemm<64,1,0><<<dim3(3,1,32), 256, 0, stream>>>(cw, qb, nullptr, 1<<30, sS,
      384, 64, 768, (long)384*768, (long)64*768, (long)384*64, projc, projq, bacq);
  k_smax_j<<<3072, 256, 0, stream>>>(sS, aP, smax);
  k_smax_i<<<32, 384, 0, stream>>>(smax, bw);
  k_q2c<<<dim3(3,32), 256, 0, stream>>>(bw, c, q2c);
  k_tq<<<dim3(12,32), 256, 0, stream>>>(qb, qT);
  k_gemm<64,0,0><<<dim3(3,12,32), 256, 0, stream>>>(aP, qT, nullptr, 1<<30, c2q,
      384, 768, 64, (long)384*64, (long)768*64, (long)384*768, nullptr, nullptr, nullptr);
  k_buildg<<<36864, 256, 0, stream>>>(c, c2q, q2c, g_bf);
  k_headsg<<<3072, 256, 0, stream>>>(g_bf, p1wg, p2wg, pg1, pg2);

  // ---- stage 1 (input 4H=3072) ----
  k_gemm<128,0,1><<<dim3(96,48,1), 256, 0, stream>>>(g_bf, l1f_wih, l1b_wih, 3072, xg,
      12288, 6144, 3072, 0, 0, 0, nullptr, nullptr, nullptr);
  k_lstm<<<96, 256, 0, stream>>>(xg, mA, l1f_whh, l1b_whh, l1f_b, l1b_b, bar);

  // ---- stage 2 (input 2H=1536) ----
  k_gemm<128,0,1><<<dim3(96,48,1), 256, 0, stream>>>(mA, l2f_wih, l2b_wih, 3072, xg,
      12288, 6144, 1536, 0, 0, 0, nullptr, nullptr, nullptr);
  k_lstm<<<96, 256, 0, stream>>>(xg, mB, l2f_whh, l2b_whh, l2f_b, l2b_b, bar + 32);
  k_headsm<<<3072, 256, 0, stream>>>(mB, p1wm, pg1, p1bg, p1bm, (float*)d_out);

  // ---- stage 3 (output LSTM, input 2H=1536) ----
  k_gemm<128,0,1><<<dim3(96,48,1), 256, 0, stream>>>(mB, lof_wih, lob_wih, 3072, xg,
      12288, 6144, 1536, 0, 0, 0, nullptr, nullptr, nullptr);
  k_lstm<<<96, 256, 0, stream>>>(xg, m2, lof_whh, lob_whh, lof_b, lob_b, bar + 64);
  k_headsm<<<3072, 256, 0, stream>>>(m2, p2wm, pg2, p2bg, p2bm, (float*)d_out + 12288);
}

// Round 4
// 9162.514 us; speedup vs baseline: 1.9517x; 1.9517x over previous
//
#include <hip/hip_runtime.h>

// ---------------------------------------------------------------------------
// BiDAF block: B=32, CLEN=384, QLEN=64, H=768
// Workspace layout (~227MB):
//   [0, 75.5MB)    g  (later: mA @0, mB @37.7MB, m2 @0)
//   [75.5, 226.5)  xg (attention temps alias the front of this region)
//   [226.5, +)     tail scalars (proj, smax, bw, q2c, pg1/pg2, barrier flags)
// R3: fence-free lstm exchange on relaxed AGENT atomics. R4 fixes R3's
// unit-size bug (8B atomic loads addressed with 16B-unit math -> half of sH
// stale => NaN): two 8B loads per 16B unit, full-row coverage.
// ---------------------------------------------------------------------------

typedef __bf16 bf16_t;
typedef __bf16 bf16x4 __attribute__((ext_vector_type(4)));
typedef __bf16 bf16x8 __attribute__((ext_vector_type(8)));
typedef float  f32x4  __attribute__((ext_vector_type(4)));

#define TT 384

__device__ __forceinline__ void gload_lds16(const void* g, void* l) {
  __builtin_amdgcn_global_load_lds((const __attribute__((address_space(1))) void*)g,
                                   (__attribute__((address_space(3))) void*)l, 16, 0, 0);
}

// zero n dwords with agent-scope stores (flag lines must not linger dirty in L2)
__global__ void k_zero(unsigned* p, int n) {
  for (int i = threadIdx.x; i < n; i += 256)
    __hip_atomic_store(p + i, 0u, __ATOMIC_RELAXED, __HIP_MEMORY_SCOPE_AGENT);
}

// ---------------------------------------------------------------------------
// GEMM: C[M,N] = A[M,K] * B[N,K]^T, A bf16 K-contig (global_load_lds).
// BSRC=0: B bf16 via global_load_lds (Bv + bz*sBb). BSRC=1: B fp32 from
// Bv (rows < nsplit) / Bv2 (rows >= nsplit), converted during staging.
// BM=128, BK=32, 256 threads = 4 waves (2x2), wave tile 64 x (BN/2).
// EPI=0: bf16 out. EPI=1: f32 out + rowb[bz*M+row] + colb[bz*N+col] + *sb.
// ---------------------------------------------------------------------------
template<int BN, int EPI, int BSRC>
__global__ __launch_bounds__(256) void k_gemm(
    const bf16_t* __restrict__ A, const void* __restrict__ Bv, const void* __restrict__ Bv2,
    int nsplit, void* __restrict__ Cv,
    int M, int N, int K, long sAb, long sBb, long sCb,
    const float* __restrict__ rowb, const float* __restrict__ colb,
    const float* __restrict__ sb)
{
  constexpr int BM = 128, BK = 32;
  constexpr int NT = BN / 32;          // 16-wide N tiles per wave
  __shared__ bf16_t sA[BM * BK];
  __shared__ bf16_t sB[BN * BK];
  const int t    = threadIdx.x;
  const int lane = t & 63;
  const int wm   = (t >> 6) >> 1, wn = (t >> 6) & 1;
  const long bz  = blockIdx.z;
  const int nbase = blockIdx.y * BN;
  const bf16_t* Ab = A + bz * sAb + (long)blockIdx.x * BM * K;
  const bf16_t* Bb = nullptr;
  const float*  Bf = nullptr;
  if constexpr (BSRC == 0)
    Bb = (const bf16_t*)Bv + bz * sBb + (long)nbase * K;
  else
    Bf = (nbase < nsplit) ? ((const float*)Bv  + (long)nbase * K)
                          : ((const float*)Bv2 + (long)(nbase - nsplit) * K);

  const int r4 = t >> 2;                          // staging row 0..63
  const int kq = (t & 3) ^ ((r4 >> 1) & 3);       // XOR-swizzled source k-quad

  f32x4 acc[4][NT];
  #pragma unroll
  for (int i = 0; i < 4; i++)
    #pragma unroll
    for (int j = 0; j < NT; j++) acc[i][j] = (f32x4){0.f, 0.f, 0.f, 0.f};

  const int mrow = lane & 15;
  const int fq   = lane >> 4;
  const int aswz = (fq ^ ((mrow >> 1) & 3)) * 8;  // swizzled frag k-offset (elems)

  for (int k0 = 0; k0 < K; k0 += BK) {
    __syncthreads();
    gload_lds16(Ab + (long)r4 * K + k0 + kq * 8,        (char*)sA + t * 16);
    gload_lds16(Ab + (long)(64 + r4) * K + k0 + kq * 8, (char*)sA + 4096 + t * 16);
    if constexpr (BSRC == 0) {
      gload_lds16(Bb + (long)r4 * K + k0 + kq * 8,        (char*)sB + t * 16);
      if constexpr (BN == 128)
        gload_lds16(Bb + (long)(64 + r4) * K + k0 + kq * 8, (char*)sB + 4096 + t * 16);
    } else {
      {
        f32x4 b0 = *(const f32x4*)(Bf + (long)r4 * K + k0 + kq * 8);
        f32x4 b1 = *(const f32x4*)(Bf + (long)r4 * K + k0 + kq * 8 + 4);
        bf16x8 bb;
        #pragma unroll
        for (int e = 0; e < 4; e++) { bb[e] = (bf16_t)b0[e]; bb[e + 4] = (bf16_t)b1[e]; }
        *(bf16x8*)((char*)sB + t * 16) = bb;
      }
      if constexpr (BN == 128) {
        f32x4 b0 = *(const f32x4*)(Bf + (long)(64 + r4) * K + k0 + kq * 8);
        f32x4 b1 = *(const f32x4*)(Bf + (long)(64 + r4) * K + k0 + kq * 8 + 4);
        bf16x8 bb;
        #pragma unroll
        for (int e = 0; e < 4; e++) { bb[e] = (bf16_t)b0[e]; bb[e + 4] = (bf16_t)b1[e]; }
        *(bf16x8*)((char*)sB + 4096 + t * 16) = bb;
      }
    }
    __syncthreads();

    bf16x8 af[4], bv[NT];
    #pragma unroll
    for (int mt = 0; mt < 4; mt++)
      af[mt] = *(const bf16x8*)(sA + (wm * 64 + mt * 16 + mrow) * 32 + aswz);
    #pragma unroll
    for (int nt = 0; nt < NT; nt++)
      bv[nt] = *(const bf16x8*)(sB + (wn * (BN / 2) + nt * 16 + mrow) * 32 + aswz);
    #pragma unroll
    for (int mt = 0; mt < 4; mt++)
      #pragma unroll
      for (int nt = 0; nt < NT; nt++)
        acc[mt][nt] = __builtin_amdgcn_mfma_f32_16x16x32_bf16(af[mt], bv[nt], acc[mt][nt], 0, 0, 0);
  }

  const int rbase = (lane >> 4) * 4;
  #pragma unroll
  for (int mt = 0; mt < 4; mt++)
    #pragma unroll
    for (int nt = 0; nt < NT; nt++)
      #pragma unroll
      for (int r = 0; r < 4; r++) {
        int grow = blockIdx.x * BM + wm * 64 + mt * 16 + rbase + r;
        int gcol = nbase + wn * (BN / 2) + nt * 16 + (lane & 15);
        if constexpr (EPI == 0) {
          ((bf16_t*)Cv)[bz * sCb + (long)grow * N + gcol] = (bf16_t)acc[mt][nt][r];
        } else {
          ((float*)Cv)[bz * sCb + (long)grow * N + gcol] =
              acc[mt][nt][r] + rowb[bz * M + grow] + colb[bz * N + gcol] + sb[0];
        }
      }
}

// ---------------------------------------------------------------------------
// Recurrent biLSTM stage. grid = 96 (48 slices x 2 dirs), 256 threads.
// Each WG: j-slice of 16 h-cols; whh rows {g*768+j0+jj} resident in LDS (bf16).
// Cross-block h exchange + per-step barrier entirely via relaxed AGENT atomics
// (LLC-coherent): NO threadfence => no per-step L2 writeback/invalidate.
// flags: one dword per block, padded to 64B lines; monotonic step counter.
// xg: [B*T, 6144] bf16 (fwd 4H | bwd 4H, gate order i,f,g,o).
// mout: [B, T, 2H] bf16 (fwd | bwd) — touched ONLY via agent atomics here.
// ---------------------------------------------------------------------------
__global__ __launch_bounds__(256) void k_lstm(
    const bf16_t* __restrict__ xg, bf16_t* __restrict__ mout,
    const float* __restrict__ whh_f, const float* __restrict__ whh_b,
    const float* __restrict__ bias_f, const float* __restrict__ bias_b,
    unsigned* __restrict__ flags)
{
  __shared__ bf16_t sW[64 * 776];   // 99,328 B
  __shared__ bf16_t sH[32 * 776];   // 49,664 B
  __shared__ float  sG[4 * 512];    //  8,192 B  => 157,184 B total (<160K)
  const int t    = threadIdx.x;
  const int lane = t & 63;
  const int wg   = t >> 6;                 // wave index == gate index
  const int blk  = blockIdx.x;
  const int dir  = blk / 48;
  const int sl   = blk - dir * 48;         // slice id within direction
  const int j0   = sl * 16;
  const float* whh  = dir ? whh_b : whh_f;
  const float* bias = dir ? bias_b : bias_f;
  unsigned* myflags = flags + dir * 48 * 16;   // 16 dwords (64B) per block

  // stage whh slice -> LDS bf16 (rows r = g*16+jj -> whh[g*768+j0+jj, :])
  for (int r = 0; r < 64; r++) {
    if (t < 192) {
      const float* src = whh + (long)((r >> 4) * 768 + j0 + (r & 15)) * 768 + t * 4;
      f32x4 v = *(const f32x4*)src;
      bf16x4 o; o[0] = (bf16_t)v[0]; o[1] = (bf16_t)v[1]; o[2] = (bf16_t)v[2]; o[3] = (bf16_t)v[3];
      *(bf16x4*)(sW + r * 776 + t * 4) = o;
    }
  }
  float bsv[4];
  #pragma unroll
  for (int gi = 0; gi < 4; gi++) bsv[gi] = bias[gi * 768 + j0 + (t & 15)];

  float cst0 = 0.f, cst1 = 0.f;
  const int mrow = lane & 15;
  const int fq   = lane >> 4;
  const int boff  = (wg * 16 + mrow) * 776 + fq * 8;
  const int aoff0 = mrow * 776 + fq * 8;
  const int aoff1 = (16 + mrow) * 776 + fq * 8;
  const int jj    = t & 15;

  for (int s = 0; s < TT; s++) {
    const int tc = dir ? (TT - 1 - s) : s;

    // prefetch this step's xg gate values (independent of h) off the
    // post-barrier critical path
    float xv[2][4];
    #pragma unroll
    for (int ui = 0; ui < 2; ui++) {
      int u = t + ui * 256;
      int b = u >> 4;
      long xr = (long)(b * TT + tc) * 6144 + dir * 3072 + j0 + (u & 15);
      #pragma unroll
      for (int gi = 0; gi < 4; gi++) xv[ui][gi] = (float)xg[xr + gi * 768];
    }

    // unit = 16B (8 bf16); 96 units per 768-bf16 row; 12 reps x 256 = 32x96
    if (s == 0) {
      #pragma unroll
      for (int rep = 0; rep < 12; rep++) {
        int e = rep * 256 + t;
        int row = e / 96, u = e - row * 96;
        char* dst = (char*)sH + row * 1552 + u * 16;
        *(unsigned long long*)dst       = 0ull;
        *(unsigned long long*)(dst + 8) = 0ull;
      }
    } else {
      // wait for all 48 slice-blocks of this direction to finish step s-1
      if (t < 64) {
        for (;;) {
          unsigned v = (lane < 48)
            ? __hip_atomic_load(myflags + lane * 16, __ATOMIC_RELAXED, __HIP_MEMORY_SCOPE_AGENT)
            : (unsigned)s;
          if (__ballot(v >= (unsigned)s) == ~0ull) break;
          __builtin_amdgcn_s_sleep(1);
        }
      }
      __syncthreads();
      const int tp = dir ? tc + 1 : tc - 1;
      const unsigned long long* src = (const unsigned long long*)mout;
      #pragma unroll
      for (int rep = 0; rep < 12; rep++) {
        int e = rep * 256 + t;
        int row = e / 96, u = e - row * 96;
        // mout row = 1536 bf16 = 384 qwords; dir half = 192 qwords
        long base = (long)(row * TT + tp) * 384 + dir * 192 + 2 * u;
        unsigned long long q0 = __hip_atomic_load(src + base,     __ATOMIC_RELAXED, __HIP_MEMORY_SCOPE_AGENT);
        unsigned long long q1 = __hip_atomic_load(src + base + 1, __ATOMIC_RELAXED, __HIP_MEMORY_SCOPE_AGENT);
        char* dst = (char*)sH + row * 1552 + u * 16;
        *(unsigned long long*)dst       = q0;
        *(unsigned long long*)(dst + 8) = q1;
      }
    }
    __syncthreads();

    f32x4 a0 = (f32x4){0.f,0.f,0.f,0.f}, a1 = (f32x4){0.f,0.f,0.f,0.f};
    #pragma unroll
    for (int kc = 0; kc < 24; kc++) {
      bf16x8 bv  = *(const bf16x8*)(sW + boff + kc * 32);
      bf16x8 av0 = *(const bf16x8*)(sH + aoff0 + kc * 32);
      bf16x8 av1 = *(const bf16x8*)(sH + aoff1 + kc * 32);
      a0 = __builtin_amdgcn_mfma_f32_16x16x32_bf16(av0, bv, a0, 0, 0, 0);
      a1 = __builtin_amdgcn_mfma_f32_16x16x32_bf16(av1, bv, a1, 0, 0, 0);
    }
    #pragma unroll
    for (int r = 0; r < 4; r++) {
      sG[wg * 512 + (fq * 4 + r) * 16 + mrow]        = a0[r];
      sG[wg * 512 + (16 + fq * 4 + r) * 16 + mrow]   = a1[r];
    }
    __syncthreads();

    #pragma unroll
    for (int ui = 0; ui < 2; ui++) {
      int u = t + ui * 256;
      int b = u >> 4;
      float gi = sG[0 * 512 + u] + xv[ui][0] + bsv[0];
      float gf = sG[1 * 512 + u] + xv[ui][1] + bsv[1];
      float gg = sG[2 * 512 + u] + xv[ui][2] + bsv[2];
      float go = sG[3 * 512 + u] + xv[ui][3] + bsv[3];
      gi = 1.f / (1.f + __expf(-gi));
      gf = 1.f / (1.f + __expf(-gf));
      gg = 1.f - 2.f / (__expf(2.f * gg) + 1.f);
      go = 1.f / (1.f + __expf(-go));
      float& cs = ui ? cst1 : cst0;
      cs = gf * cs + gi * gg;
      float hv = go * (1.f - 2.f / (__expf(2.f * cs) + 1.f));
      // pack 2 adjacent bf16 (jj even | jj odd) into one dword, store agent-scope
      float hp = __shfl_xor(hv, 1);
      if (!(jj & 1)) {
        union { bf16_t b2[2]; unsigned u32; } pk;
        pk.b2[0] = (bf16_t)hv; pk.b2[1] = (bf16_t)hp;
        __hip_atomic_store(
            (unsigned*)mout + (long)(b * TT + tc) * 768 + dir * 384 + ((j0 + jj) >> 1),
            pk.u32, __ATOMIC_RELAXED, __HIP_MEMORY_SCOPE_AGENT);
      }
    }

    // all waves drain their stores (implicit vmcnt(0) before s_barrier), then
    // one lane publishes this block's step-complete flag
    __syncthreads();
    if (t == 0)
      __hip_atomic_store(myflags + sl * 16, (unsigned)(s + 1),
                         __ATOMIC_RELAXED, __HIP_MEMORY_SCOPE_AGENT);
  }
}

// --------------------------- attention helpers -----------------------------

__global__ __launch_bounds__(256) void k_pack(
    const float* __restrict__ c, const float* __restrict__ q,
    const float* __restrict__ wcq, bf16_t* __restrict__ cw, bf16_t* __restrict__ qb)
{
  int i = blockIdx.x * 256 + threadIdx.x;        // 43008 blocks -> 11,010,048
  if (i < 9437184) {
    int h = i % 768;
    cw[i] = (bf16_t)(c[i] * wcq[h]);
  } else {
    int j = i - 9437184;
    qb[j] = (bf16_t)q[j];
  }
}

__global__ __launch_bounds__(256) void k_proj(
    const float* __restrict__ c, const float* __restrict__ q,
    const float* __restrict__ wc, const float* __restrict__ bc,
    const float* __restrict__ wq, const float* __restrict__ bq,
    float* __restrict__ projc, float* __restrict__ projq)
{
  int row  = blockIdx.x * 4 + (threadIdx.x >> 6);  // 0..14335
  int lane = threadIdx.x & 63;
  const float *src, *w;
  bool isC = row < 12288;
  if (isC) { src = c + (long)row * 768;          w = wc; }
  else     { src = q + (long)(row - 12288) * 768; w = wq; }
  float a = 0.f;
  for (int k = lane * 4; k < 768; k += 256) {
    f32x4 v = *(const f32x4*)(src + k);
    f32x4 wv = *(const f32x4*)(w + k);
    a += v[0]*wv[0] + v[1]*wv[1] + v[2]*wv[2] + v[3]*wv[3];
  }
  for (int m = 32; m; m >>= 1) a += __shfl_xor(a, m);
  if (lane == 0) {
    if (isC) projc[row] = a + bc[0];
    else     projq[row - 12288] = a + bq[0];
  }
}

__global__ __launch_bounds__(256) void k_smax_j(
    const float* __restrict__ s, bf16_t* __restrict__ a, float* __restrict__ smax)
{
  int row  = blockIdx.x * 4 + (threadIdx.x >> 6);
  int lane = threadIdx.x & 63;
  float v = s[(long)row * 64 + lane];
  float mx = v;
  for (int m = 32; m; m >>= 1) mx = fmaxf(mx, __shfl_xor(mx, m));
  float p = __expf(v - mx);
  float sum = p;
  for (int m = 32; m; m >>= 1) sum += __shfl_xor(sum, m);
  a[(long)row * 64 + lane] = (bf16_t)(p / sum);
  if (lane == 0) smax[row] = mx;
}

__global__ __launch_bounds__(384) void k_smax_i(
    const float* __restrict__ smax, float* __restrict__ bw)
{
  __shared__ float red[8];
  int b = blockIdx.x, t = threadIdx.x;   // 384 threads, 6 waves
  int lane = t & 63, wv = t >> 6;
  float v = smax[b * 384 + t];
  float mx = v;
  for (int m = 32; m; m >>= 1) mx = fmaxf(mx, __shfl_xor(mx, m));
  if (lane == 0) red[wv] = mx;
  __syncthreads();
  float gm = red[0];
  #pragma unroll
  for (int i = 1; i < 6; i++) gm = fmaxf(gm, red[i]);
  float p = __expf(v - gm);
  float sm = p;
  for (int m = 32; m; m >>= 1) sm += __shfl_xor(sm, m);
  __syncthreads();
  if (lane == 0) red[wv] = sm;
  __syncthreads();
  float tot = red[0];
  #pragma unroll
  for (int i = 1; i < 6; i++) tot += red[i];
  bw[b * 384 + t] = p / tot;
}

__global__ __launch_bounds__(256) void k_q2c(
    const float* __restrict__ bw, const float* __restrict__ c, float* __restrict__ q2c)
{
  int b = blockIdx.y;
  int h = blockIdx.x * 256 + threadIdx.x;
  const float* cb = c + (long)b * 384 * 768;
  float acc = 0.f;
  for (int i = 0; i < 384; i++) acc += bw[b * 384 + i] * cb[(long)i * 768 + h];
  q2c[b * 768 + h] = acc;
}

__global__ __launch_bounds__(256) void k_tq(
    const bf16_t* __restrict__ qb, bf16_t* __restrict__ qT)
{
  __shared__ bf16_t sT[64][72];
  int b = blockIdx.y, hc = blockIdx.x, t = threadIdx.x;
  {
    int j = t >> 2, h0 = (t & 3) * 16;
    const bf16_t* src = qb + (long)(b * 64 + j) * 768 + hc * 64 + h0;
    *(bf16x8*)&sT[j][h0]     = *(const bf16x8*)(src);
    *(bf16x8*)&sT[j][h0 + 8] = *(const bf16x8*)(src + 8);
  }
  __syncthreads();
  {
    int h = t >> 2, j0 = (t & 3) * 16;
    bf16x8 o0, o1;
    #pragma unroll
    for (int e = 0; e < 8; e++) { o0[e] = sT[j0 + e][h]; o1[e] = sT[j0 + 8 + e][h]; }
    bf16_t* dst = qT + (long)(b * 768 + hc * 64 + h) * 64 + j0;
    *(bf16x8*)dst       = o0;
    *(bf16x8*)(dst + 8) = o1;
  }
}

__global__ __launch_bounds__(256) void k_buildg(
    const float* __restrict__ c, const bf16_t* __restrict__ c2q,
    const float* __restrict__ q2c, bf16_t* __restrict__ g)
{
  int i = blockIdx.x * 256 + threadIdx.x;   // < 9,437,184
  int h = i % 768;
  int row = i / 768;
  int b = row / 384;
  float cv  = c[i];
  float cqv = (float)c2q[i];
  float qcv = q2c[b * 768 + h];
  bf16_t* gr = g + (long)row * 3072;
  gr[h]        = (bf16_t)cv;
  gr[768 + h]  = c2q[i];
  gr[1536 + h] = (bf16_t)(cv * cqv);
  gr[2304 + h] = (bf16_t)(cv * qcv);
}

// heads: g-part (both p1 and p2), one pass over g
__global__ __launch_bounds__(256) void k_headsg(
    const bf16_t* __restrict__ g, const float* __restrict__ w1, const float* __restrict__ w2,
    float* __restrict__ pg1, float* __restrict__ pg2)
{
  int row  = blockIdx.x * 4 + (threadIdx.x >> 6);  // 0..12287
  int lane = threadIdx.x & 63;
  float a1 = 0.f, a2 = 0.f;
  const bf16_t* gr = g + (long)row * 3072;
  for (int k = lane * 8; k < 3072; k += 512) {
    bf16x8 v = *(const bf16x8*)(gr + k);
    f32x4 wa = *(const f32x4*)(w1 + k), wb = *(const f32x4*)(w1 + k + 4);
    f32x4 xa = *(const f32x4*)(w2 + k), xb = *(const f32x4*)(w2 + k + 4);
    #pragma unroll
    for (int e = 0; e < 4; e++) {
      a1 += (float)v[e] * wa[e] + (float)v[e + 4] * wb[e];
      a2 += (float)v[e] * xa[e] + (float)v[e + 4] * xb[e];
    }
  }
  for (int m_ = 32; m_; m_ >>= 1) { a1 += __shfl_xor(a1, m_); a2 += __shfl_xor(a2, m_); }
  if (lane == 0) { pg1[row] = a1; pg2[row] = a2; }
}

// heads: m-part, writes final output rows
__global__ __launch_bounds__(256) void k_headsm(
    const bf16_t* __restrict__ m, const float* __restrict__ wm,
    const float* __restrict__ pg, const float* __restrict__ bg,
    const float* __restrict__ bm, float* __restrict__ out)
{
  int row  = blockIdx.x * 4 + (threadIdx.x >> 6);  // 0..12287
  int lane = threadIdx.x & 63;
  float a = 0.f;
  const bf16_t* mr = m + (long)row * 1536;
  for (int k = lane * 8; k < 1536; k += 512) {
    bf16x8 v = *(const bf16x8*)(mr + k);
    f32x4 wa = *(const f32x4*)(wm + k), wb = *(const f32x4*)(wm + k + 4);
    #pragma unroll
    for (int e = 0; e < 4; e++) a += (float)v[e] * wa[e] + (float)v[e + 4] * wb[e];
  }
  for (int m_ = 32; m_; m_ >>= 1) a += __shfl_xor(a, m_);
  if (lane == 0) out[row] = pg[row] + a + bg[0] + bm[0];
}

// ---------------------------------------------------------------------------

extern "C" void kernel_launch(void* const* d_in, const int* in_sizes, int n_in,
                              void* d_out, int out_size, void* d_ws, size_t ws_size,
                              hipStream_t stream)
{
  (void)in_sizes; (void)n_in; (void)out_size; (void)ws_size;
  const float* c    = (const float*)d_in[0];
  const float* q    = (const float*)d_in[1];
  const float* wac  = (const float*)d_in[2];
  const float* bac  = (const float*)d_in[3];
  const float* waq  = (const float*)d_in[4];
  const float* baq  = (const float*)d_in[5];
  const float* wacq = (const float*)d_in[6];
  const float* bacq = (const float*)d_in[7];
  const float* l1f_wih = (const float*)d_in[8];
  const float* l1f_whh = (const float*)d_in[9];
  const float* l1f_b   = (const float*)d_in[10];
  const float* l1b_wih = (const float*)d_in[11];
  const float* l1b_whh = (const float*)d_in[12];
  const float* l1b_b   = (const float*)d_in[13];
  const float* l2f_wih = (const float*)d_in[14];
  const float* l2f_whh = (const float*)d_in[15];
  const float* l2f_b   = (const float*)d_in[16];
  const float* l2b_wih = (const float*)d_in[17];
  const float* l2b_whh = (const float*)d_in[18];
  const float* l2b_b   = (const float*)d_in[19];
  const float* lof_wih = (const float*)d_in[20];
  const float* lof_whh = (const float*)d_in[21];
  const float* lof_b   = (const float*)d_in[22];
  const float* lob_wih = (const float*)d_in[23];
  const float* lob_whh = (const float*)d_in[24];
  const float* lob_b   = (const float*)d_in[25];
  const float* p1wg = (const float*)d_in[26];
  const float* p1bg = (const float*)d_in[27];
  const float* p1wm = (const float*)d_in[28];
  const float* p1bm = (const float*)d_in[29];
  const float* p2wg = (const float*)d_in[30];
  const float* p2bg = (const float*)d_in[31];
  const float* p2wm = (const float*)d_in[32];
  const float* p2bm = (const float*)d_in[33];

  // workspace layout (total ~226.9 MB)
  char* ws = (char*)d_ws;
  bf16_t* g_bf = (bf16_t*)ws;                       // [0, 75.5MB) g
  bf16_t* mA   = (bf16_t*)ws;                       // aliases g (g dead by stage1 lstm)
  bf16_t* mB   = (bf16_t*)(ws + 37748736L);         // second half of g region
  bf16_t* m2   = (bf16_t*)ws;                       // aliases mA (dead after stage2 GEMM)
  char*   xgc  = ws + 75497472L;                    // [75.5MB, 226.5MB) xg
  bf16_t* xg   = (bf16_t*)xgc;
  // attention temps alias the xg region (dead before stage1 GEMM writes xg)
  bf16_t* cw  = (bf16_t*)xgc;                       // 18,874,368
  bf16_t* qb  = (bf16_t*)(xgc + 18874368L);         //  3,145,728
  bf16_t* qT  = (bf16_t*)(xgc + 22020096L);         //  3,145,728
  float*  sS  = (float*) (xgc + 25165824L);         //  3,145,728
  bf16_t* aP  = (bf16_t*)(xgc + 28311552L);         //  1,572,864
  bf16_t* c2q = (bf16_t*)(xgc + 29884416L);         // 18,874,368
  char* tail = ws + 226492416L;
  float*    projc = (float*)tail;                   // 49,152
  float*    projq = (float*)(tail + 49152);         //  8,192
  float*    smax  = (float*)(tail + 57344);         // 49,152
  float*    bw    = (float*)(tail + 106496);        // 49,152
  float*    q2c   = (float*)(tail + 155648);        // 98,304
  float*    pg1   = (float*)(tail + 253952);        // 49,152
  float*    pg2   = (float*)(tail + 303104);        // 49,152
  unsigned* flags = (unsigned*)(tail + 352256);     // 3 stages x 2 dirs x 48 x 64B

  k_zero<<<1, 256, 0, stream>>>(flags, 4608);

  // ---- attention ----
  k_pack<<<43008, 256, 0, stream>>>(c, q, wacq, cw, qb);
  k_proj<<<3584, 256, 0, stream>>>(c, q, wac, bac, waq, baq, projc, projq);
  k_gemm<64,1,0><<<dim3(3,1,32), 256, 0, stream>>>(cw, qb, nullptr, 1<<30, sS,
      384, 64, 768, (long)384*768, (long)64*768, (long)384*64, projc, projq, bacq);
  k_smax_j<<<3072, 256, 0, stream>>>(sS, aP, smax);
  k_smax_i<<<32, 384, 0, stream>>>(smax, bw);
  k_q2c<<<dim3(3,32), 256, 0, stream>>>(bw, c, q2c);
  k_tq<<<dim3(12,32), 256, 0, stream>>>(qb, qT);
  k_gemm<64,0,0><<<dim3(3,12,32), 256, 0, stream>>>(aP, qT, nullptr, 1<<30, c2q,
      384, 768, 64, (long)384*64, (long)768*64, (long)384*768, nullptr, nullptr, nullptr);
  k_buildg<<<36864, 256, 0, stream>>>(c, c2q, q2c, g_bf);
  k_headsg<<<3072, 256, 0, stream>>>(g_bf, p1wg, p2wg, pg1, pg2);

  // ---- stage 1 (input 4H=3072) ----
  k_gemm<128,0,1><<<dim3(96,48,1), 256, 0, stream>>>(g_bf, l1f_wih, l1b_wih, 3072, xg,
      12288, 6144, 3072, 0, 0, 0, nullptr, nullptr, nullptr);
  k_lstm<<<96, 256, 0, stream>>>(xg, mA, l1f_whh, l1b_whh, l1f_b, l1b_b, flags);

  // ---- stage 2 (input 2H=1536) ----
  k_gemm<128,0,1><<<dim3(96,48,1), 256, 0, stream>>>(mA, l2f_wih, l2b_wih, 3072, xg,
      12288, 6144, 1536, 0, 0, 0, nullptr, nullptr, nullptr);
  k_lstm<<<96, 256, 0, stream>>>(xg, mB, l2f_whh, l2b_whh, l2f_b, l2b_b, flags + 1536);
  k_headsm<<<3072, 256, 0, stream>>>(mB, p1wm, pg1, p1bg, p1bm, (float*)d_out);

  // ---- stage 3 (output LSTM, input 2H=1536) ----
  k_gemm<128,0,1><<<dim3(96,48,1), 256, 0, stream>>>(mB, lof_wih, lob_wih, 3072, xg,
      12288, 6144, 1536, 0, 0, 0, nullptr, nullptr, nullptr);
  k_lstm<<<96, 256, 0, stream>>>(xg, m2, lof_whh, lob_whh, lof_b, lob_b, flags + 3072);
  k_headsm<<<3072, 256, 0, stream>>>(m2, p2wm, pg2, p2bg, p2bm, (float*)d_out + 12288);
}

// Round 5
// 6966.914 us; speedup vs baseline: 2.5668x; 1.3151x over previous
//
#include <hip/hip_runtime.h>

// ---------------------------------------------------------------------------
// BiDAF block: B=32, CLEN=384, QLEN=64, H=768
// Workspace layout (~228MB):
//   [0, 75.5MB)    g  (later: mA @0, mB @37.7MB, m2 @0)
//   [75.5, 226.5)  xg (attention temps alias the front of this region)
//   [226.5, +)     tail scalars + E exchange buffer (786KB)
// R5: k_lstm exchange = tag-in-data dwords {tag:16|bf16 h:16} in LLC-resident
// E buffer, parity double-buffered. Consumers poll data tags directly: one
// LLC round trip per step, no flags/barrier/drain. Batch-split bg=2 (192
// blocks, 16 batches each, LDS 128KB).
// ---------------------------------------------------------------------------

typedef __bf16 bf16_t;
typedef __bf16 bf16x4 __attribute__((ext_vector_type(4)));
typedef __bf16 bf16x8 __attribute__((ext_vector_type(8)));
typedef float  f32x4  __attribute__((ext_vector_type(4)));
typedef unsigned long long ull;

#define TT 384

__device__ __forceinline__ void gload_lds16(const void* g, void* l) {
  __builtin_amdgcn_global_load_lds((const __attribute__((address_space(1))) void*)g,
                                   (__attribute__((address_space(3))) void*)l, 16, 0, 0);
}

// set all E tags to 0xFFFF (never matches a wanted tag in [0,1152))
__global__ void k_zeroE(unsigned* p) {
  int i = blockIdx.x * 256 + threadIdx.x;
  __hip_atomic_store(p + i, 0xFFFF0000u, __ATOMIC_RELAXED, __HIP_MEMORY_SCOPE_AGENT);
}

// ---------------------------------------------------------------------------
// GEMM: C[M,N] = A[M,K] * B[N,K]^T, A bf16 K-contig (global_load_lds).
// BSRC=0: B bf16 via global_load_lds (Bv + bz*sBb). BSRC=1: B fp32 from
// Bv (rows < nsplit) / Bv2 (rows >= nsplit), converted during staging.
// BM=128, BK=32, 256 threads = 4 waves (2x2), wave tile 64 x (BN/2).
// EPI=0: bf16 out. EPI=1: f32 out + rowb[bz*M+row] + colb[bz*N+col] + *sb.
// ---------------------------------------------------------------------------
template<int BN, int EPI, int BSRC>
__global__ __launch_bounds__(256) void k_gemm(
    const bf16_t* __restrict__ A, const void* __restrict__ Bv, const void* __restrict__ Bv2,
    int nsplit, void* __restrict__ Cv,
    int M, int N, int K, long sAb, long sBb, long sCb,
    const float* __restrict__ rowb, const float* __restrict__ colb,
    const float* __restrict__ sb)
{
  constexpr int BM = 128, BK = 32;
  constexpr int NT = BN / 32;          // 16-wide N tiles per wave
  __shared__ bf16_t sA[BM * BK];
  __shared__ bf16_t sB[BN * BK];
  const int t    = threadIdx.x;
  const int lane = t & 63;
  const int wm   = (t >> 6) >> 1, wn = (t >> 6) & 1;
  const long bz  = blockIdx.z;
  const int nbase = blockIdx.y * BN;
  const bf16_t* Ab = A + bz * sAb + (long)blockIdx.x * BM * K;
  const bf16_t* Bb = nullptr;
  const float*  Bf = nullptr;
  if constexpr (BSRC == 0)
    Bb = (const bf16_t*)Bv + bz * sBb + (long)nbase * K;
  else
    Bf = (nbase < nsplit) ? ((const float*)Bv  + (long)nbase * K)
                          : ((const float*)Bv2 + (long)(nbase - nsplit) * K);

  const int r4 = t >> 2;                          // staging row 0..63
  const int kq = (t & 3) ^ ((r4 >> 1) & 3);       // XOR-swizzled source k-quad

  f32x4 acc[4][NT];
  #pragma unroll
  for (int i = 0; i < 4; i++)
    #pragma unroll
    for (int j = 0; j < NT; j++) acc[i][j] = (f32x4){0.f, 0.f, 0.f, 0.f};

  const int mrow = lane & 15;
  const int fq   = lane >> 4;
  const int aswz = (fq ^ ((mrow >> 1) & 3)) * 8;  // swizzled frag k-offset (elems)

  for (int k0 = 0; k0 < K; k0 += BK) {
    __syncthreads();
    gload_lds16(Ab + (long)r4 * K + k0 + kq * 8,        (char*)sA + t * 16);
    gload_lds16(Ab + (long)(64 + r4) * K + k0 + kq * 8, (char*)sA + 4096 + t * 16);
    if constexpr (BSRC == 0) {
      gload_lds16(Bb + (long)r4 * K + k0 + kq * 8,        (char*)sB + t * 16);
      if constexpr (BN == 128)
        gload_lds16(Bb + (long)(64 + r4) * K + k0 + kq * 8, (char*)sB + 4096 + t * 16);
    } else {
      {
        f32x4 b0 = *(const f32x4*)(Bf + (long)r4 * K + k0 + kq * 8);
        f32x4 b1 = *(const f32x4*)(Bf + (long)r4 * K + k0 + kq * 8 + 4);
        bf16x8 bb;
        #pragma unroll
        for (int e = 0; e < 4; e++) { bb[e] = (bf16_t)b0[e]; bb[e + 4] = (bf16_t)b1[e]; }
        *(bf16x8*)((char*)sB + t * 16) = bb;
      }
      if constexpr (BN == 128) {
        f32x4 b0 = *(const f32x4*)(Bf + (long)(64 + r4) * K + k0 + kq * 8);
        f32x4 b1 = *(const f32x4*)(Bf + (long)(64 + r4) * K + k0 + kq * 8 + 4);
        bf16x8 bb;
        #pragma unroll
        for (int e = 0; e < 4; e++) { bb[e] = (bf16_t)b0[e]; bb[e + 4] = (bf16_t)b1[e]; }
        *(bf16x8*)((char*)sB + 4096 + t * 16) = bb;
      }
    }
    __syncthreads();

    bf16x8 af[4], bv[NT];
    #pragma unroll
    for (int mt = 0; mt < 4; mt++)
      af[mt] = *(const bf16x8*)(sA + (wm * 64 + mt * 16 + mrow) * 32 + aswz);
    #pragma unroll
    for (int nt = 0; nt < NT; nt++)
      bv[nt] = *(const bf16x8*)(sB + (wn * (BN / 2) + nt * 16 + mrow) * 32 + aswz);
    #pragma unroll
    for (int mt = 0; mt < 4; mt++)
      #pragma unroll
      for (int nt = 0; nt < NT; nt++)
        acc[mt][nt] = __builtin_amdgcn_mfma_f32_16x16x32_bf16(af[mt], bv[nt], acc[mt][nt], 0, 0, 0);
  }

  const int rbase = (lane >> 4) * 4;
  #pragma unroll
  for (int mt = 0; mt < 4; mt++)
    #pragma unroll
    for (int nt = 0; nt < NT; nt++)
      #pragma unroll
      for (int r = 0; r < 4; r++) {
        int grow = blockIdx.x * BM + wm * 64 + mt * 16 + rbase + r;
        int gcol = nbase + wn * (BN / 2) + nt * 16 + (lane & 15);
        if constexpr (EPI == 0) {
          ((bf16_t*)Cv)[bz * sCb + (long)grow * N + gcol] = (bf16_t)acc[mt][nt][r];
        } else {
          ((float*)Cv)[bz * sCb + (long)grow * N + gcol] =
              acc[mt][nt][r] + rowb[bz * M + grow] + colb[bz * N + gcol] + sb[0];
        }
      }
}

// ---------------------------------------------------------------------------
// Recurrent biLSTM stage. grid = 192: dir(2) x slice(48) x bg(2).
// Block owns 16 h-cols x 16 batches; whh slice resident in LDS bf16.
// Exchange: E dwords {tag:16 | bf16 h:16}, parity double-buffered, relaxed
// AGENT atomics (LLC). Consumers poll tags directly — no flags, no barrier.
// tag = tagbase + step (tagbase = stage*384; retagged to 0xFFFF up front).
// xg: [B*T, 6144] bf16 (fwd 4H | bwd 4H, gate order i,f,g,o).
// mout: [B, T, 2H] bf16 (fwd | bwd) — plain stores, for downstream kernels.
// ---------------------------------------------------------------------------
__global__ __launch_bounds__(256) void k_lstm(
    const bf16_t* __restrict__ xg, bf16_t* __restrict__ mout,
    unsigned* __restrict__ E,
    const float* __restrict__ whh_f, const float* __restrict__ whh_b,
    const float* __restrict__ bias_f, const float* __restrict__ bias_b,
    int tagbase)
{
  __shared__ bf16_t sW[64 * 776];   // 99,328 B
  __shared__ bf16_t sH[16 * 776];   // 24,832 B
  __shared__ float  sG[4 * 256];    //  4,096 B  => 128,256 B total
  const int t    = threadIdx.x;
  const int lane = t & 63;
  const int wg   = t >> 6;                 // wave index == gate index
  const int blk  = blockIdx.x;
  const int dir  = blk / 96;
  const int qq   = blk - dir * 96;
  const int sl   = qq >> 1;                // slice 0..47
  const int bg   = qq & 1;                 // batch group 0..1
  const int j0   = sl * 16;
  const float* whh  = dir ? whh_b : whh_f;
  const float* bias = dir ? bias_b : bias_f;

  // stage whh slice -> LDS bf16 (rows r = g*16+jj -> whh[g*768+j0+jj, :])
  for (int r = 0; r < 64; r++) {
    if (t < 192) {
      const float* src = whh + (long)((r >> 4) * 768 + j0 + (r & 15)) * 768 + t * 4;
      f32x4 v = *(const f32x4*)src;
      bf16x4 o; o[0] = (bf16_t)v[0]; o[1] = (bf16_t)v[1]; o[2] = (bf16_t)v[2]; o[3] = (bf16_t)v[3];
      *(bf16x4*)(sW + r * 776 + t * 4) = o;
    }
  }
  const int b16 = t >> 4;                  // local batch 0..15
  const int jj  = t & 15;                  // local col 0..15
  float bsv[4];
  #pragma unroll
  for (int gi = 0; gi < 4; gi++) bsv[gi] = bias[gi * 768 + j0 + jj];

  // loop-invariant consumer offsets: e = i*256+t covers 16 batches x 384 qwords
  int soff[24];
  #pragma unroll
  for (int i = 0; i < 24; i++) {
    int e = i * 256 + t;
    soff[i] = (e / 384) * 1552 + (e % 384) * 4;  // sH byte offset (2 bf16 per qword)
  }

  float cst = 0.f;
  const int mrow  = lane & 15;
  const int fq    = lane >> 4;
  const int boff  = (wg * 16 + mrow) * 776 + fq * 8;
  const int aoff0 = mrow * 776 + fq * 8;
  const long xrow0 = (long)(bg * 16 + b16) * TT;

  for (int s = 0; s < TT; s++) {
    const int tc = dir ? (TT - 1 - s) : s;

    // prefetch this step's xg gate values (independent of h)
    float xv[4];
    {
      long xr = (xrow0 + tc) * 6144 + dir * 3072 + j0 + jj;
      #pragma unroll
      for (int gi = 0; gi < 4; gi++) xv[gi] = (float)xg[xr + gi * 768];
    }

    if (s == 0) {
      for (int e = t; e < 1552; e += 256)
        *(f32x4*)((char*)sH + e * 16) = (f32x4){0.f, 0.f, 0.f, 0.f};
    } else {
      const unsigned want = (unsigned)(tagbase + s - 1);
      const int par = (s - 1) & 1;
      const ull* src = (const ull*)E + ((long)(par * 2 + dir) * 32 + bg * 16) * 384;
      ull qv[24];
      #pragma unroll
      for (int i = 0; i < 24; i++)
        qv[i] = __hip_atomic_load(src + i * 256 + t, __ATOMIC_RELAXED, __HIP_MEMORY_SCOPE_AGENT);
      for (;;) {
        unsigned bad = 0;
        #pragma unroll
        for (int i = 0; i < 24; i++) {
          unsigned lo = (unsigned)qv[i], hi = (unsigned)(qv[i] >> 32);
          if ((lo >> 16) != want || (hi >> 16) != want) bad |= 1u << i;
        }
        if (!bad) break;
        #pragma unroll
        for (int i = 0; i < 24; i++)
          if (bad & (1u << i))
            qv[i] = __hip_atomic_load(src + i * 256 + t, __ATOMIC_RELAXED, __HIP_MEMORY_SCOPE_AGENT);
      }
      #pragma unroll
      for (int i = 0; i < 24; i++) {
        ushort2 hh;
        hh.x = (unsigned short)qv[i];
        hh.y = (unsigned short)(qv[i] >> 32);
        *(ushort2*)((char*)sH + soff[i]) = hh;
      }
    }
    __syncthreads();

    f32x4 a0 = (f32x4){0.f, 0.f, 0.f, 0.f};
    #pragma unroll
    for (int kc = 0; kc < 24; kc++) {
      bf16x8 bv = *(const bf16x8*)(sW + boff + kc * 32);
      bf16x8 av = *(const bf16x8*)(sH + aoff0 + kc * 32);
      a0 = __builtin_amdgcn_mfma_f32_16x16x32_bf16(av, bv, a0, 0, 0, 0);
    }
    #pragma unroll
    for (int r = 0; r < 4; r++)
      sG[wg * 256 + (fq * 4 + r) * 16 + mrow] = a0[r];
    __syncthreads();

    {
      float gi = sG[0 * 256 + t] + xv[0] + bsv[0];
      float gf = sG[1 * 256 + t] + xv[1] + bsv[1];
      float gg = sG[2 * 256 + t] + xv[2] + bsv[2];
      float go = sG[3 * 256 + t] + xv[3] + bsv[3];
      gi = 1.f / (1.f + __expf(-gi));
      gf = 1.f / (1.f + __expf(-gf));
      gg = 1.f - 2.f / (__expf(2.f * gg) + 1.f);
      go = 1.f / (1.f + __expf(-go));
      cst = gf * cst + gi * gg;
      float hv = go * (1.f - 2.f / (__expf(2.f * cst) + 1.f));
      union { bf16_t b; unsigned short u; } pk;
      pk.b = (bf16_t)hv;
      unsigned tag = (unsigned)(tagbase + s);
      long ed = ((long)((s & 1) * 2 + dir) * 32 + bg * 16 + b16) * 768 + j0 + jj;
      __hip_atomic_store(E + ed, (tag << 16) | pk.u,
                         __ATOMIC_RELAXED, __HIP_MEMORY_SCOPE_AGENT);
      mout[(xrow0 + tc) * 1536 + dir * 768 + j0 + jj] = pk.b;
    }
    // no end-of-step barrier: next iteration's sH overwrite is fenced by the
    // post-fill __syncthreads (all threads passed MFMA+sG by then)
  }
}

// --------------------------- attention helpers -----------------------------

__global__ __launch_bounds__(256) void k_pack(
    const float* __restrict__ c, const float* __restrict__ q,
    const float* __restrict__ wcq, bf16_t* __restrict__ cw, bf16_t* __restrict__ qb)
{
  int i = blockIdx.x * 256 + threadIdx.x;        // 43008 blocks -> 11,010,048
  if (i < 9437184) {
    int h = i % 768;
    cw[i] = (bf16_t)(c[i] * wcq[h]);
  } else {
    int j = i - 9437184;
    qb[j] = (bf16_t)q[j];
  }
}

__global__ __launch_bounds__(256) void k_proj(
    const float* __restrict__ c, const float* __restrict__ q,
    const float* __restrict__ wc, const float* __restrict__ bc,
    const float* __restrict__ wq, const float* __restrict__ bq,
    float* __restrict__ projc, float* __restrict__ projq)
{
  int row  = blockIdx.x * 4 + (threadIdx.x >> 6);  // 0..14335
  int lane = threadIdx.x & 63;
  const float *src, *w;
  bool isC = row < 12288;
  if (isC) { src = c + (long)row * 768;          w = wc; }
  else     { src = q + (long)(row - 12288) * 768; w = wq; }
  float a = 0.f;
  for (int k = lane * 4; k < 768; k += 256) {
    f32x4 v = *(const f32x4*)(src + k);
    f32x4 wv = *(const f32x4*)(w + k);
    a += v[0]*wv[0] + v[1]*wv[1] + v[2]*wv[2] + v[3]*wv[3];
  }
  for (int m = 32; m; m >>= 1) a += __shfl_xor(a, m);
  if (lane == 0) {
    if (isC) projc[row] = a + bc[0];
    else     projq[row - 12288] = a + bq[0];
  }
}

__global__ __launch_bounds__(256) void k_smax_j(
    const float* __restrict__ s, bf16_t* __restrict__ a, float* __restrict__ smax)
{
  int row  = blockIdx.x * 4 + (threadIdx.x >> 6);
  int lane = threadIdx.x & 63;
  float v = s[(long)row * 64 + lane];
  float mx = v;
  for (int m = 32; m; m >>= 1) mx = fmaxf(mx, __shfl_xor(mx, m));
  float p = __expf(v - mx);
  float sum = p;
  for (int m = 32; m; m >>= 1) sum += __shfl_xor(sum, m);
  a[(long)row * 64 + lane] = (bf16_t)(p / sum);
  if (lane == 0) smax[row] = mx;
}

__global__ __launch_bounds__(384) void k_smax_i(
    const float* __restrict__ smax, float* __restrict__ bw)
{
  __shared__ float red[8];
  int b = blockIdx.x, t = threadIdx.x;   // 384 threads, 6 waves
  int lane = t & 63, wv = t >> 6;
  float v = smax[b * 384 + t];
  float mx = v;
  for (int m = 32; m; m >>= 1) mx = fmaxf(mx, __shfl_xor(mx, m));
  if (lane == 0) red[wv] = mx;
  __syncthreads();
  float gm = red[0];
  #pragma unroll
  for (int i = 1; i < 6; i++) gm = fmaxf(gm, red[i]);
  float p = __expf(v - gm);
  float sm = p;
  for (int m = 32; m; m >>= 1) sm += __shfl_xor(sm, m);
  __syncthreads();
  if (lane == 0) red[wv] = sm;
  __syncthreads();
  float tot = red[0];
  #pragma unroll
  for (int i = 1; i < 6; i++) tot += red[i];
  bw[b * 384 + t] = p / tot;
}

__global__ __launch_bounds__(256) void k_q2c(
    const float* __restrict__ bw, const float* __restrict__ c, float* __restrict__ q2c)
{
  int b = blockIdx.y;
  int h = blockIdx.x * 256 + threadIdx.x;
  const float* cb = c + (long)b * 384 * 768;
  float acc = 0.f;
  for (int i = 0; i < 384; i++) acc += bw[b * 384 + i] * cb[(long)i * 768 + h];
  q2c[b * 768 + h] = acc;
}

__global__ __launch_bounds__(256) void k_tq(
    const bf16_t* __restrict__ qb, bf16_t* __restrict__ qT)
{
  __shared__ bf16_t sT[64][72];
  int b = blockIdx.y, hc = blockIdx.x, t = threadIdx.x;
  {
    int j = t >> 2, h0 = (t & 3) * 16;
    const bf16_t* src = qb + (long)(b * 64 + j) * 768 + hc * 64 + h0;
    *(bf16x8*)&sT[j][h0]     = *(const bf16x8*)(src);
    *(bf16x8*)&sT[j][h0 + 8] = *(const bf16x8*)(src + 8);
  }
  __syncthreads();
  {
    int h = t >> 2, j0 = (t & 3) * 16;
    bf16x8 o0, o1;
    #pragma unroll
    for (int e = 0; e < 8; e++) { o0[e] = sT[j0 + e][h]; o1[e] = sT[j0 + 8 + e][h]; }
    bf16_t* dst = qT + (long)(b * 768 + hc * 64 + h) * 64 + j0;
    *(bf16x8*)dst       = o0;
    *(bf16x8*)(dst + 8) = o1;
  }
}

__global__ __launch_bounds__(256) void k_buildg(
    const float* __restrict__ c, const bf16_t* __restrict__ c2q,
    const float* __restrict__ q2c, bf16_t* __restrict__ g)
{
  int i = blockIdx.x * 256 + threadIdx.x;   // < 9,437,184
  int h = i % 768;
  int row = i / 768;
  int b = row / 384;
  float cv  = c[i];
  float cqv = (float)c2q[i];
  float qcv = q2c[b * 768 + h];
  bf16_t* gr = g + (long)row * 3072;
  gr[h]        = (bf16_t)cv;
  gr[768 + h]  = c2q[i];
  gr[1536 + h] = (bf16_t)(cv * cqv);
  gr[2304 + h] = (bf16_t)(cv * qcv);
}

// heads: g-part (both p1 and p2), one pass over g
__global__ __launch_bounds__(256) void k_headsg(
    const bf16_t* __restrict__ g, const float* __restrict__ w1, const float* __restrict__ w2,
    float* __restrict__ pg1, float* __restrict__ pg2)
{
  int row  = blockIdx.x * 4 + (threadIdx.x >> 6);  // 0..12287
  int lane = threadIdx.x & 63;
  float a1 = 0.f, a2 = 0.f;
  const bf16_t* gr = g + (long)row * 3072;
  for (int k = lane * 8; k < 3072; k += 512) {
    bf16x8 v = *(const bf16x8*)(gr + k);
    f32x4 wa = *(const f32x4*)(w1 + k), wb = *(const f32x4*)(w1 + k + 4);
    f32x4 xa = *(const f32x4*)(w2 + k), xb = *(const f32x4*)(w2 + k + 4);
    #pragma unroll
    for (int e = 0; e < 4; e++) {
      a1 += (float)v[e] * wa[e] + (float)v[e + 4] * wb[e];
      a2 += (float)v[e] * xa[e] + (float)v[e + 4] * xb[e];
    }
  }
  for (int m_ = 32; m_; m_ >>= 1) { a1 += __shfl_xor(a1, m_); a2 += __shfl_xor(a2, m_); }
  if (lane == 0) { pg1[row] = a1; pg2[row] = a2; }
}

// heads: m-part, writes final output rows
__global__ __launch_bounds__(256) void k_headsm(
    const bf16_t* __restrict__ m, const float* __restrict__ wm,
    const float* __restrict__ pg, const float* __restrict__ bg,
    const float* __restrict__ bm, float* __restrict__ out)
{
  int row  = blockIdx.x * 4 + (threadIdx.x >> 6);  // 0..12287
  int lane = threadIdx.x & 63;
  float a = 0.f;
  const bf16_t* mr = m + (long)row * 1536;
  for (int k = lane * 8; k < 1536; k += 512) {
    bf16x8 v = *(const bf16x8*)(mr + k);
    f32x4 wa = *(const f32x4*)(wm + k), wb = *(const f32x4*)(wm + k + 4);
    #pragma unroll
    for (int e = 0; e < 4; e++) a += (float)v[e] * wa[e] + (float)v[e + 4] * wb[e];
  }
  for (int m_ = 32; m_; m_ >>= 1) a += __shfl_xor(a, m_);
  if (lane == 0) out[row] = pg[row] + a + bg[0] + bm[0];
}

// ---------------------------------------------------------------------------

extern "C" void kernel_launch(void* const* d_in, const int* in_sizes, int n_in,
                              void* d_out, int out_size, void* d_ws, size_t ws_size,
                              hipStream_t stream)
{
  (void)in_sizes; (void)n_in; (void)out_size; (void)ws_size;
  const float* c    = (const float*)d_in[0];
  const float* q    = (const float*)d_in[1];
  const float* wac  = (const float*)d_in[2];
  const float* bac  = (const float*)d_in[3];
  const float* waq  = (const float*)d_in[4];
  const float* baq  = (const float*)d_in[5];
  const float* wacq = (const float*)d_in[6];
  const float* bacq = (const float*)d_in[7];
  const float* l1f_wih = (const float*)d_in[8];
  const float* l1f_whh = (const float*)d_in[9];
  const float* l1f_b   = (const float*)d_in[10];
  const float* l1b_wih = (const float*)d_in[11];
  const float* l1b_whh = (const float*)d_in[12];
  const float* l1b_b   = (const float*)d_in[13];
  const float* l2f_wih = (const float*)d_in[14];
  const float* l2f_whh = (const float*)d_in[15];
  const float* l2f_b   = (const float*)d_in[16];
  const float* l2b_wih = (const float*)d_in[17];
  const float* l2b_whh = (const float*)d_in[18];
  const float* l2b_b   = (const float*)d_in[19];
  const float* lof_wih = (const float*)d_in[20];
  const float* lof_whh = (const float*)d_in[21];
  const float* lof_b   = (const float*)d_in[22];
  const float* lob_wih = (const float*)d_in[23];
  const float* lob_whh = (const float*)d_in[24];
  const float* lob_b   = (const float*)d_in[25];
  const float* p1wg = (const float*)d_in[26];
  const float* p1bg = (const float*)d_in[27];
  const float* p1wm = (const float*)d_in[28];
  const float* p1bm = (const float*)d_in[29];
  const float* p2wg = (const float*)d_in[30];
  const float* p2bg = (const float*)d_in[31];
  const float* p2wm = (const float*)d_in[32];
  const float* p2bm = (const float*)d_in[33];

  // workspace layout (total ~227.6 MB)
  char* ws = (char*)d_ws;
  bf16_t* g_bf = (bf16_t*)ws;                       // [0, 75.5MB) g
  bf16_t* mA   = (bf16_t*)ws;                       // aliases g (g dead by stage1 lstm)
  bf16_t* mB   = (bf16_t*)(ws + 37748736L);         // second half of g region
  bf16_t* m2   = (bf16_t*)ws;                       // aliases mA (dead after stage2 GEMM)
  char*   xgc  = ws + 75497472L;                    // [75.5MB, 226.5MB) xg
  bf16_t* xg   = (bf16_t*)xgc;
  // attention temps alias the xg region (dead before stage1 GEMM writes xg)
  bf16_t* cw  = (bf16_t*)xgc;                       // 18,874,368
  bf16_t* qb  = (bf16_t*)(xgc + 18874368L);         //  3,145,728
  bf16_t* qT  = (bf16_t*)(xgc + 22020096L);         //  3,145,728
  float*  sS  = (float*) (xgc + 25165824L);         //  3,145,728
  bf16_t* aP  = (bf16_t*)(xgc + 28311552L);         //  1,572,864
  bf16_t* c2q = (bf16_t*)(xgc + 29884416L);         // 18,874,368
  char* tail = ws + 226492416L;
  float*    projc = (float*)tail;                   // 49,152
  float*    projq = (float*)(tail + 49152);         //  8,192
  float*    smax  = (float*)(tail + 57344);         // 49,152
  float*    bw    = (float*)(tail + 106496);        // 49,152
  float*    q2c   = (float*)(tail + 155648);        // 98,304
  float*    pg1   = (float*)(tail + 253952);        // 49,152
  float*    pg2   = (float*)(tail + 303104);        // 49,152
  unsigned* E     = (unsigned*)(tail + 352256);     // 2par x 2dir x 32 x 768 x 4B = 786,432

  k_zeroE<<<768, 256, 0, stream>>>(E);

  // ---- attention ----
  k_pack<<<43008, 256, 0, stream>>>(c, q, wacq, cw, qb);
  k_proj<<<3584, 256, 0, stream>>>(c, q, wac, bac, waq, baq, projc, projq);
  k_gemm<64,1,0><<<dim3(3,1,32), 256, 0, stream>>>(cw, qb, nullptr, 1<<30, sS,
      384, 64, 768, (long)384*768, (long)64*768, (long)384*64, projc, projq, bacq);
  k_smax_j<<<3072, 256, 0, stream>>>(sS, aP, smax);
  k_smax_i<<<32, 384, 0, stream>>>(smax, bw);
  k_q2c<<<dim3(3,32), 256, 0, stream>>>(bw, c, q2c);
  k_tq<<<dim3(12,32), 256, 0, stream>>>(qb, qT);
  k_gemm<64,0,0><<<dim3(3,12,32), 256, 0, stream>>>(aP, qT, nullptr, 1<<30, c2q,
      384, 768, 64, (long)384*64, (long)768*64, (long)384*768, nullptr, nullptr, nullptr);
  k_buildg<<<36864, 256, 0, stream>>>(c, c2q, q2c, g_bf);
  k_headsg<<<3072, 256, 0, stream>>>(g_bf, p1wg, p2wg, pg1, pg2);

  // ---- stage 1 (input 4H=3072) ----
  k_gemm<128,0,1><<<dim3(96,48,1), 256, 0, stream>>>(g_bf, l1f_wih, l1b_wih, 3072, xg,
      12288, 6144, 3072, 0, 0, 0, nullptr, nullptr, nullptr);
  k_lstm<<<192, 256, 0, stream>>>(xg, mA, E, l1f_whh, l1b_whh, l1f_b, l1b_b, 0);

  // ---- stage 2 (input 2H=1536) ----
  k_gemm<128,0,1><<<dim3(96,48,1), 256, 0, stream>>>(mA, l2f_wih, l2b_wih, 3072, xg,
      12288, 6144, 1536, 0, 0, 0, nullptr, nullptr, nullptr);
  k_lstm<<<192, 256, 0, stream>>>(xg, mB, E, l2f_whh, l2b_whh, l2f_b, l2b_b, 384);
  k_headsm<<<3072, 256, 0, stream>>>(mB, p1wm, pg1, p1bg, p1bm, (float*)d_out);

  // ---- stage 3 (output LSTM, input 2H=1536) ----
  k_gemm<128,0,1><<<dim3(96,48,1), 256, 0, stream>>>(mB, lof_wih, lob_wih, 3072, xg,
      12288, 6144, 1536, 0, 0, 0, nullptr, nullptr, nullptr);
  k_lstm<<<192, 256, 0, stream>>>(xg, m2, E, lof_whh, lob_whh, lof_b, lob_b, 768);
  k_headsm<<<3072, 256, 0, stream>>>(m2, p2wm, pg2, p2bg, p2bm, (float*)d_out + 12288);
}